// Round 8
// baseline (94.074 us; speedup 1.0000x reference)
//
#include <hip/hip_runtime.h>

// ConditionalPreactivation: out = Z @ Wflat + bf @ bvec,
//   Z[b, k*512+i] = bf[b,k] * a[b,i],  a = lrelu(LN(x)),  bf = basis(c).
// 256x256 GEMM with FINE 4-phase-per-K-tile schedule (m201-style): per phase
// {ds_read subtile + staged GL16 issue -> barrier -> 16 MFMA -> barrier},
// staging spread across phases, counted vmcnt(8) once per tile.
// bf applied in-register on A-fragments.  Split-K=8 -> grid 256 (1/CU).
// B=4096, DIN=512, DOUT=512, DC=64, K=16, DB=256.

#define LRELU(v) ((v) >= 0.f ? (v) : 0.01f * (v))

typedef _Float16 f16x8 __attribute__((ext_vector_type(8)));
typedef float f32x4 __attribute__((ext_vector_type(4)));

#define GL16(gp, lp) __builtin_amdgcn_global_load_lds(                      \
    (const __attribute__((address_space(1))) void*)(gp),                    \
    (__attribute__((address_space(3))) void*)(lp), 16, 0, 0)

#define MFMA16(a, b, c) __builtin_amdgcn_mfma_f32_16x16x32_f16((a), (b), (c), 0, 0, 0)

#define BAR() do { __builtin_amdgcn_sched_barrier(0);                       \
                   __builtin_amdgcn_s_barrier();                            \
                   __builtin_amdgcn_sched_barrier(0); } while (0)

// ---------------------------------------------------------------------------
// Fused prep: blocks [0,512)      basis functions -> bf f32  (8 rows/block)
//             blocks [512,1536)   W f32 -> Wt f16 transposed [o][k*512+i]
//             blocks [1536,2560)  LayerNorm+lrelu -> a f16
// [UNCHANGED from round 7]
// ---------------------------------------------------------------------------
__global__ __launch_bounds__(256) void prep_kernel(
    const float* __restrict__ x, const float* __restrict__ gam,
    const float* __restrict__ bet, _Float16* __restrict__ a,
    const float* __restrict__ c, const float* __restrict__ w1,
    const float* __restrict__ b1, const float* __restrict__ wr,
    const float* __restrict__ br, const float* __restrict__ w2,
    const float* __restrict__ b2, float* __restrict__ bfo,
    const float* __restrict__ W, _Float16* __restrict__ Wt)
{
    __shared__ __align__(16) char smem[18432];
    int tid = threadIdx.x;
    int blk = blockIdx.x;

    if (blk < 512) {
        float* c_l  = (float*)smem;             // 8*64  = 2 KB
        float* lr_l = (float*)(smem + 2048);    // 8*256 = 8 KB
        float* h_l  = (float*)(smem + 10240);   // 8*256 = 8 KB
        int b0 = blk * 8;

        for (int i = tid; i < 8 * 64; i += 256) c_l[i] = c[(size_t)b0 * 64 + i];

        float w1c[64];
#pragma unroll
        for (int u = 0; u < 64; ++u) w1c[u] = w1[u * 256 + tid];
        float b1s = b1[tid];
        __syncthreads();

        float h1[8];
#pragma unroll
        for (int r = 0; r < 8; ++r) h1[r] = b1s;
#pragma unroll
        for (int j4 = 0; j4 < 16; ++j4) {
#pragma unroll
            for (int r = 0; r < 8; ++r) {
                float4 cv = *(const float4*)&c_l[r * 64 + j4 * 4];
                h1[r] += cv.x * w1c[j4 * 4 + 0] + cv.y * w1c[j4 * 4 + 1] +
                         cv.z * w1c[j4 * 4 + 2] + cv.w * w1c[j4 * 4 + 3];
            }
        }
#pragma unroll
        for (int r = 0; r < 8; ++r) lr_l[r * 256 + tid] = LRELU(h1[r]);
        __syncthreads();

        float brv = br[tid];
        float h2[8];
#pragma unroll
        for (int r = 0; r < 8; ++r) h2[r] = h1[r] + brv;

#pragma unroll 1
        for (int jc = 0; jc < 8; ++jc) {
            float w8[32];
#pragma unroll
            for (int u = 0; u < 32; ++u) w8[u] = wr[(jc * 32 + u) * 256 + tid];
#pragma unroll
            for (int j4 = 0; j4 < 8; ++j4) {
#pragma unroll
                for (int r = 0; r < 8; ++r) {
                    float4 lv = *(const float4*)&lr_l[r * 256 + jc * 32 + j4 * 4];
                    h2[r] += lv.x * w8[j4 * 4 + 0] + lv.y * w8[j4 * 4 + 1] +
                             lv.z * w8[j4 * 4 + 2] + lv.w * w8[j4 * 4 + 3];
                }
            }
        }
#pragma unroll
        for (int r = 0; r < 8; ++r) h_l[r * 256 + tid] = LRELU(h2[r]);
        __syncthreads();

        if (tid < 128) {
            int r = tid >> 4, k = tid & 15;
            float s = b2[k];
#pragma unroll 1
            for (int qc = 0; qc < 8; ++qc) {
                float wv[32];
#pragma unroll
                for (int u = 0; u < 32; ++u) wv[u] = w2[(qc * 32 + u) * 16 + k];
#pragma unroll
                for (int q4 = 0; q4 < 8; ++q4) {
                    float4 hv = *(const float4*)&h_l[r * 256 + qc * 32 + q4 * 4];
                    s += hv.x * wv[q4 * 4 + 0] + hv.y * wv[q4 * 4 + 1] +
                         hv.z * wv[q4 * 4 + 2] + hv.w * wv[q4 * 4 + 3];
                }
            }
            bfo[(size_t)(b0 + r) * 16 + k] = s;
        }

    } else if (blk < 1536) {
        float* t = (float*)smem;  // 64*65*4 = 16.25 KB
        int bid = blk - 512;
        int k  = bid >> 6;
        int it = (bid >> 3) & 7;
        int ot = bid & 7;
        int i0 = it * 64, o0 = ot * 64;

        int rr = tid >> 4, c4 = (tid & 15) * 4;
#pragma unroll
        for (int p = 0; p < 4; ++p) {
            int r = p * 16 + rr;
            float4 v = *(const float4*)&W[((size_t)(k * 512 + i0 + r)) * 512 + o0 + c4];
            t[r * 65 + c4 + 0] = v.x;
            t[r * 65 + c4 + 1] = v.y;
            t[r * 65 + c4 + 2] = v.z;
            t[r * 65 + c4 + 3] = v.w;
        }
        __syncthreads();

        int ol = tid >> 2, c0 = (tid & 3) * 16;
        _Float16 hb[16] __attribute__((aligned(16)));
#pragma unroll
        for (int u = 0; u < 16; ++u) hb[u] = (_Float16)t[(c0 + u) * 65 + ol];
        _Float16* dst = &Wt[(size_t)(o0 + ol) * 8192 + k * 512 + i0 + c0];
        *(float4*)dst       = *(const float4*)&hb[0];
        *(float4*)(dst + 8) = *(const float4*)&hb[8];

    } else {
        int lane = tid & 63;
        int row  = (blk - 1536) * 4 + (tid >> 6);
        const float* xr = x + (size_t)row * 512 + lane * 8;
        float4 v0 = *(const float4*)xr;
        float4 v1 = *(const float4*)(xr + 4);

        float s = v0.x + v0.y + v0.z + v0.w + v1.x + v1.y + v1.z + v1.w;
#pragma unroll
        for (int m = 1; m < 64; m <<= 1) s += __shfl_xor(s, m);
        float mean = s * (1.f / 512.f);

        float d, s2 = 0.f;
        d = v0.x - mean; s2 += d * d;
        d = v0.y - mean; s2 += d * d;
        d = v0.z - mean; s2 += d * d;
        d = v0.w - mean; s2 += d * d;
        d = v1.x - mean; s2 += d * d;
        d = v1.y - mean; s2 += d * d;
        d = v1.z - mean; s2 += d * d;
        d = v1.w - mean; s2 += d * d;
#pragma unroll
        for (int m = 1; m < 64; m <<= 1) s2 += __shfl_xor(s2, m);
        float rstd = rsqrtf(s2 * (1.f / 512.f) + 1e-5f);

        float4 g0 = *(const float4*)&gam[lane * 8];
        float4 g1 = *(const float4*)&gam[lane * 8 + 4];
        float4 b0 = *(const float4*)&bet[lane * 8];
        float4 b1v = *(const float4*)&bet[lane * 8 + 4];

        _Float16 o8[8] __attribute__((aligned(16)));
        float y;
        y = (v0.x - mean) * rstd * g0.x + b0.x;  y = LRELU(y); o8[0] = (_Float16)y;
        y = (v0.y - mean) * rstd * g0.y + b0.y;  y = LRELU(y); o8[1] = (_Float16)y;
        y = (v0.z - mean) * rstd * g0.z + b0.z;  y = LRELU(y); o8[2] = (_Float16)y;
        y = (v0.w - mean) * rstd * g0.w + b0.w;  y = LRELU(y); o8[3] = (_Float16)y;
        y = (v1.x - mean) * rstd * g1.x + b1v.x; y = LRELU(y); o8[4] = (_Float16)y;
        y = (v1.y - mean) * rstd * g1.y + b1v.y; y = LRELU(y); o8[5] = (_Float16)y;
        y = (v1.z - mean) * rstd * g1.z + b1v.z; y = LRELU(y); o8[6] = (_Float16)y;
        y = (v1.w - mean) * rstd * g1.w + b1v.w; y = LRELU(y); o8[7] = (_Float16)y;

        *(float4*)&a[(size_t)row * 512 + lane * 8] = *(const float4*)o8;
    }
}

// ---------------------------------------------------------------------------
// Main GEMM, fine 4-phase schedule per K-tile of 64.
// Per wave (2Mx4N grid): output 128x64 = 8f x 4nf fragments, 64 MFMA/tile.
// Phase q computes fragments f=2q,2q+1 (16 MFMA).  B (8 b128) read in P0,
// held in regs across the tile.  Staging of tile t+2 into buf[t&1]:
//   P1: B rounds 0,1       (B region fully consumed in P0)
//   P2: B rounds 2,3 + A rounds 0,2  (A rows 0-63/128-191 consumed in P0-P1)
//   tail: A rounds 1,3     (A rows 64-127/192-255 consumed in P2-P3)
//   then vmcnt(8) = all of tile t+1 landed, t+2's 8 still in flight.
// ---------------------------------------------------------------------------
template <int NSPLIT>
__global__ __launch_bounds__(512, 2) void gemm_kernel(
    const _Float16* __restrict__ A,   // [4096][512]
    const _Float16* __restrict__ Wt,  // [512][8192]
    const float* __restrict__ bfg,    // [4096][16]
    float* __restrict__ pout)         // [NSPLIT][4096][512]
{
    constexpr int KTN = 16 / NSPLIT;   // kt-groups per block
    constexpr int NT  = KTN * 8;       // K-tiles of 64

    __shared__ _Float16 As[2][256 * 64];  // 64 KB
    __shared__ _Float16 Bs[2][256 * 64];  // 64 KB

    const int tid = threadIdx.x;
    const int bid = blockIdx.x;
    const int split = bid % NSPLIT;
    const int mn  = bid / NSPLIT;
    const int n0  = (mn & 1) * 256;
    const int bm0 = (mn >> 1) * 256;
    const int kt0 = split * KTN;

    const int lane = tid & 63, wid = tid >> 6;
    const int wm = wid >> 2, wn = wid & 3;   // 2 x 4 wave grid
    const int l16 = lane & 15, lg = lane >> 4;

    // per-lane A-row scales: row = bm0 + wm*128 + f*16 + l16
    _Float16 s16[KTN][8];
#pragma unroll
    for (int kt = 0; kt < KTN; ++kt)
#pragma unroll
        for (int f = 0; f < 8; ++f)
            s16[kt][f] = (_Float16)
                bfg[(size_t)(bm0 + wm * 128 + f * 16 + l16) * 16 + kt0 + kt];

    // staging: chunk = p*512+tid -> row = p*64 + (tid>>3), col-chunk c = tid&7;
    // inverse-swizzled global source chunk = c ^ (row&7)
    const int brow = tid >> 3;
    const int swc  = (tid & 7) ^ (brow & 7);
    const _Float16* aAs = A  + (size_t)(bm0 + brow) * 512  + swc * 8;
    const _Float16* aBs = Wt + (size_t)(n0  + brow) * 8192 + swc * 8;

    auto STAGE = [&](int t, int buf) {   // full-tile stage (prologue only)
        const int ka = (t & 7) * 64;
        const size_t kb = (size_t)(kt0 + (t >> 3)) * 512 + ka;
        char* la = (char*)&As[buf][0] + tid * 16;
        char* lb = (char*)&Bs[buf][0] + tid * 16;
#pragma unroll
        for (int p = 0; p < 4; ++p) {
            GL16(aAs + (size_t)(p * 64) * 512 + ka, la + p * 8192);
            GL16(aBs + (size_t)(p * 64) * 8192 + kb, lb + p * 8192);
        }
    };

    // swizzled ds_read offsets
    const int swr = l16 & 7;
    const int aRowByte = (wm * 128 + l16) * 128;
    const int bRowByte = (wn * 64 + l16) * 128;
    const int sw0 = ((0 + lg) ^ swr) << 4;   // kk = 0
    const int sw1 = ((4 + lg) ^ swr) << 4;   // kk = 1

    const f32x4 z4 = {0.f, 0.f, 0.f, 0.f};
    f32x4 acc[8][4];
#pragma unroll
    for (int f = 0; f < 8; ++f)
#pragma unroll
        for (int nf = 0; nf < 4; ++nf) acc[f][nf] = z4;

    // prologue: stage tiles 0,1; wait tile 0 (8 of 16 outstanding)
    STAGE(0, 0);
    STAGE(1, 1);
    asm volatile("s_waitcnt vmcnt(8)" ::: "memory");
    BAR();

#define AREAD(q)                                                            \
    xa = *(const f16x8*)(Ab + aRowByte + (2 * (q) + 0) * 2048 + sw0);       \
    xb = *(const f16x8*)(Ab + aRowByte + (2 * (q) + 0) * 2048 + sw1);       \
    xc = *(const f16x8*)(Ab + aRowByte + (2 * (q) + 1) * 2048 + sw0);       \
    xd = *(const f16x8*)(Ab + aRowByte + (2 * (q) + 1) * 2048 + sw1);

#define MFMAQ(q)                                                            \
    {                                                                       \
        const _Float16 sA = s16[kt][2 * (q) + 0];                           \
        const _Float16 sB = s16[kt][2 * (q) + 1];                           \
        xa *= sA; xb *= sA; xc *= sB; xd *= sB;                             \
        __builtin_amdgcn_s_setprio(1);                                      \
        acc[2*(q)+0][0] = MFMA16(xa, bA0, acc[2*(q)+0][0]);                 \
        acc[2*(q)+0][0] = MFMA16(xb, bA1, acc[2*(q)+0][0]);                 \
        acc[2*(q)+0][1] = MFMA16(xa, bB0, acc[2*(q)+0][1]);                 \
        acc[2*(q)+0][1] = MFMA16(xb, bB1, acc[2*(q)+0][1]);                 \
        acc[2*(q)+0][2] = MFMA16(xa, bC0, acc[2*(q)+0][2]);                 \
        acc[2*(q)+0][2] = MFMA16(xb, bC1, acc[2*(q)+0][2]);                 \
        acc[2*(q)+0][3] = MFMA16(xa, bD0, acc[2*(q)+0][3]);                 \
        acc[2*(q)+0][3] = MFMA16(xb, bD1, acc[2*(q)+0][3]);                 \
        acc[2*(q)+1][0] = MFMA16(xc, bA0, acc[2*(q)+1][0]);                 \
        acc[2*(q)+1][0] = MFMA16(xd, bA1, acc[2*(q)+1][0]);                 \
        acc[2*(q)+1][1] = MFMA16(xc, bB0, acc[2*(q)+1][1]);                 \
        acc[2*(q)+1][1] = MFMA16(xd, bB1, acc[2*(q)+1][1]);                 \
        acc[2*(q)+1][2] = MFMA16(xc, bC0, acc[2*(q)+1][2]);                 \
        acc[2*(q)+1][2] = MFMA16(xd, bC1, acc[2*(q)+1][2]);                 \
        acc[2*(q)+1][3] = MFMA16(xc, bD0, acc[2*(q)+1][3]);                 \
        acc[2*(q)+1][3] = MFMA16(xd, bD1, acc[2*(q)+1][3]);                 \
        __builtin_amdgcn_s_setprio(0);                                      \
    }

#pragma unroll
    for (int kt = 0; kt < KTN; ++kt) {
#pragma unroll 1
        for (int t2 = 0; t2 < 8; ++t2) {
            const int t = kt * 8 + t2;
            const int cur = t & 1;
            const char* Ab = (const char*)&As[cur][0];
            const char* Bb = (const char*)&Bs[cur][0];
            const int tt = t + 2;                 // tile being staged (into buf cur)
            const bool st = (tt < NT);
            char* sAd = (char*)&As[cur][0] + tid * 16;
            char* sBd = (char*)&Bs[cur][0] + tid * 16;
            const int ka = (tt & 7) * 64;
            const size_t kb = (size_t)(kt0 + (tt >> 3)) * 512 + ka;

            f16x8 xa, xb, xc, xd;

            // ---- P0: B all (8 reads) + A q0 (4 reads)
            f16x8 bA0 = *(const f16x8*)(Bb + bRowByte + 0 * 2048 + sw0);
            f16x8 bA1 = *(const f16x8*)(Bb + bRowByte + 0 * 2048 + sw1);
            f16x8 bB0 = *(const f16x8*)(Bb + bRowByte + 1 * 2048 + sw0);
            f16x8 bB1 = *(const f16x8*)(Bb + bRowByte + 1 * 2048 + sw1);
            f16x8 bC0 = *(const f16x8*)(Bb + bRowByte + 2 * 2048 + sw0);
            f16x8 bC1 = *(const f16x8*)(Bb + bRowByte + 2 * 2048 + sw1);
            f16x8 bD0 = *(const f16x8*)(Bb + bRowByte + 3 * 2048 + sw0);
            f16x8 bD1 = *(const f16x8*)(Bb + bRowByte + 3 * 2048 + sw1);
            AREAD(0);
            BAR();
            MFMAQ(0);
            BAR();

            // ---- P1: A q1; stage B rounds 0,1 of tile t+2
            AREAD(1);
            if (st) {
                GL16(aBs + (size_t)(0 * 64) * 8192 + kb, sBd + 0 * 8192);
                GL16(aBs + (size_t)(1 * 64) * 8192 + kb, sBd + 1 * 8192);
            }
            BAR();
            MFMAQ(1);
            BAR();

            // ---- P2: A q2; stage B rounds 2,3 + A rounds 0,2
            AREAD(2);
            if (st) {
                GL16(aBs + (size_t)(2 * 64) * 8192 + kb, sBd + 2 * 8192);
                GL16(aBs + (size_t)(3 * 64) * 8192 + kb, sBd + 3 * 8192);
                GL16(aAs + (size_t)(0 * 64) * 512 + ka, sAd + 0 * 8192);
                GL16(aAs + (size_t)(2 * 64) * 512 + ka, sAd + 2 * 8192);
            }
            BAR();
            MFMAQ(2);
            BAR();

            // ---- P3: A q3
            AREAD(3);
            BAR();
            MFMAQ(3);
            BAR();

            // ---- tail: stage A rounds 1,3; counted vmcnt
            if (st) {
                GL16(aAs + (size_t)(1 * 64) * 512 + ka, sAd + 1 * 8192);
                GL16(aAs + (size_t)(3 * 64) * 512 + ka, sAd + 3 * 8192);
                asm volatile("s_waitcnt vmcnt(8)" ::: "memory");
            } else {
                asm volatile("s_waitcnt vmcnt(0)" ::: "memory");
            }
            BAR();
        }
    }
#undef AREAD
#undef MFMAQ

    // ---- epilogue: plain stores to this split's partial buffer
    float* op = pout + (size_t)split * (4096 * 512);
#pragma unroll
    for (int f = 0; f < 8; ++f)
#pragma unroll
        for (int j = 0; j < 4; ++j) {
            const int grow = bm0 + wm * 128 + f * 16 + lg * 4 + j;
            float* orow = op + (size_t)grow * 512 + n0 + wn * 64 + l16;
#pragma unroll
            for (int nf = 0; nf < 4; ++nf)
                orow[nf * 16] = acc[f][nf][j];
        }
}

// ---------------------------------------------------------------------------
// out = sum over splits of partials + bf @ bvec.  One float4 per thread.
// ---------------------------------------------------------------------------
__global__ __launch_bounds__(256) void reduce_kernel(const float* __restrict__ p,
                                                     const float* __restrict__ bfg,
                                                     const float* __restrict__ bvec,
                                                     float* __restrict__ out,
                                                     int nsplit)
{
    size_t i = (size_t)blockIdx.x * 256 + threadIdx.x;  // float4 index
    const float4* p4 = (const float4*)p;
    float4 s = p4[i];
    for (int sp = 1; sp < nsplit; ++sp) {
        float4 v = p4[i + (size_t)sp * 524288];
        s.x += v.x; s.y += v.y; s.z += v.z; s.w += v.w;
    }
    int b = (int)(i >> 7);        // 128 float4 per row
    int c = (int)(i & 127);
    const float* bfr = bfg + (size_t)b * 16;
    const float4* bv4 = (const float4*)bvec;  // [16][128] float4
#pragma unroll
    for (int k = 0; k < 16; ++k) {
        float bk = bfr[k];
        float4 v = bv4[k * 128 + c];
        s.x += bk * v.x; s.y += bk * v.y; s.z += bk * v.z; s.w += bk * v.w;
    }
    ((float4*)out)[i] = s;
}

// ---------------------------------------------------------------------------
extern "C" void kernel_launch(void* const* d_in, const int* in_sizes, int n_in,
                              void* d_out, int out_size, void* d_ws, size_t ws_size,
                              hipStream_t stream)
{
    const float* x    = (const float*)d_in[0];
    const float* c    = (const float*)d_in[1];
    const float* gam  = (const float*)d_in[2];
    const float* bet  = (const float*)d_in[3];
    const float* w1   = (const float*)d_in[4];
    const float* b1   = (const float*)d_in[5];
    const float* wr   = (const float*)d_in[6];
    const float* br   = (const float*)d_in[7];
    const float* w2   = (const float*)d_in[8];
    const float* b2   = (const float*)d_in[9];
    const float* W    = (const float*)d_in[10];
    const float* bvec = (const float*)d_in[11];
    float* out = (float*)d_out;

    const size_t outBytes  = (size_t)4096 * 512 * 4;                  // 8 MB
    const size_t miscBytes = (8u << 20) + (4u << 20) + (256u << 10);  // Wt+a+bf

    // nsplit=8 needs 76.25 MB of ws (selected successfully rounds 4-7).
    int nsplit = (ws_size >= 8 * outBytes + miscBytes) ? 8 : 4;

    char* ws = (char*)d_ws;
    size_t pbytes = (size_t)nsplit * outBytes;
    float*    part = (float*)ws;
    _Float16* Wt   = (_Float16*)(ws + pbytes);
    _Float16* af   = (_Float16*)(ws + pbytes + (8u << 20));
    float*    bf   = (float*)(ws + pbytes + (12u << 20));

    prep_kernel<<<dim3(2560), dim3(256), 0, stream>>>(
        x, gam, bet, af, c, w1, b1, wr, br, w2, b2, bf, W, Wt);

    if (nsplit == 8) {
        // 16 m-tiles * 2 n-tiles * 8 splits = 256 blocks (1 per CU)
        gemm_kernel<8><<<dim3(256), dim3(512), 0, stream>>>(af, Wt, bf, part);
    } else {
        gemm_kernel<4><<<dim3(128), dim3(512), 0, stream>>>(af, Wt, bf, part);
    }
    reduce_kernel<<<dim3(2048), dim3(256), 0, stream>>>(part, bf, bvec, out, nsplit);
}